// Round 1
// baseline (2630.124 us; speedup 1.0000x reference)
//
#include <hip/hip_runtime.h>

#define HID 128
#define INP 64
#define SPAN 8
#define NOUT 2
#define DAYS 20
#define BR 32            // rows per block
#define HPAD 132         // padded h row stride (floats); 132%4==0 -> 16B aligned rows
#define NTH 256

__device__ __forceinline__ float sigf(float x) { return 1.0f / (1.0f + __expf(-x)); }
__device__ __forceinline__ float tanh_(float x) { return 1.0f - 2.0f / (1.0f + __expf(2.0f * x)); }

__global__ __launch_bounds__(NTH, 2) void gru_all(
    const float* __restrict__ hx,
    const float* __restrict__ w_ih,
    const float* __restrict__ w_hh,
    const float* __restrict__ b_ih,
    const float* __restrict__ b_hh,
    const float* __restrict__ fc_in_w,
    const float* __restrict__ fc_in_b,
    const float* __restrict__ fc_out_w,
    const float* __restrict__ fc_out_b,
    const float* __restrict__ span_w,
    const float* __restrict__ span_b,
    float* __restrict__ out, int bs)
{
    __shared__ float h_lds[BR * HPAD];
    __shared__ float x_lds[BR * INP];

    const int tid  = threadIdx.x;
    const int row0 = blockIdx.x * BR;

    // ---- load hx tile (32 rows x 128 f32) coalesced as float4 ----
    {
        const float4* src = (const float4*)hx + (size_t)row0 * (HID / 4);
        #pragma unroll
        for (int i = 0; i < (BR * HID / 4) / NTH; ++i) {
            int t4 = tid + NTH * i;          // 0..1023
            int r  = t4 >> 5;                // 32 float4 per row
            int c  = t4 & 31;
            float4 v = src[r * (HID / 4) + c];
            *(float4*)&h_lds[r * HPAD + c * 4] = v;
        }
    }
    for (int i = tid; i < BR * INP; i += NTH) x_lds[i] = 0.0f;  // x0 = zeros
    __syncthreads();

    // ---- num_spans = softmax(hx @ span_w.T + span_b) ----
    {
        const int r = tid >> 3, s = tid & 7;     // 32 rows x 8 spans = 256 threads
        float acc = span_b[s];
        const float* wr = span_w + (size_t)s * HID;
        #pragma unroll
        for (int k = 0; k < HID; k += 4) {
            const float4 w4 = *(const float4*)&wr[k];
            const float4 h4 = *(const float4*)&h_lds[r * HPAD + k];
            acc = fmaf(h4.x, w4.x, acc); acc = fmaf(h4.y, w4.y, acc);
            acc = fmaf(h4.z, w4.z, acc); acc = fmaf(h4.w, w4.w, acc);
        }
        float m = acc;
        #pragma unroll
        for (int d = 1; d < SPAN; d <<= 1) m = fmaxf(m, __shfl_xor(m, d));
        const float e = __expf(acc - m);
        float ssum = e;
        #pragma unroll
        for (int d = 1; d < SPAN; d <<= 1) ssum += __shfl_xor(ssum, d);
        out[(size_t)(row0 + r) * SPAN + s] = e / ssum;
    }

    // ---- per-thread gate column j (0..127), row parity rr (0..1) ----
    const int j  = tid & (HID - 1);
    const int rr = tid >> 7;
    const float bR  = b_ih[j]           + b_hh[j];
    const float bZ  = b_ih[HID + j]     + b_hh[HID + j];
    const float bNi = b_ih[2 * HID + j];
    const float bNh = b_hh[2 * HID + j];
    const float* __restrict__ whhR = w_hh + (size_t)j * HID;
    const float* __restrict__ whhZ = w_hh + (size_t)(HID + j) * HID;
    const float* __restrict__ whhN = w_hh + (size_t)(2 * HID + j) * HID;
    const float* __restrict__ wihR = w_ih + (size_t)j * INP;
    const float* __restrict__ wihZ = w_ih + (size_t)(HID + j) * INP;
    const float* __restrict__ wihN = w_ih + (size_t)(2 * HID + j) * INP;

    const int jx  = tid & (INP - 1);
    const int rg4 = tid >> 6;                       // 0..3
    const float* __restrict__ fiw = fc_in_w + (size_t)jx * HID;
    const float fib = fc_in_b[jx];

    float* __restrict__ outp = out + (size_t)bs * SPAN;

    for (int day = 0; day < DAYS; ++day) {
        float aR[16], aZ[16], aNi[16], aNh[16];
        #pragma unroll
        for (int i = 0; i < 16; ++i) { aR[i] = bR; aZ[i] = bZ; aNi[i] = bNi; aNh[i] = bNh; }

        // gh: h @ w_hh.T  (K=128). LDS h reads are wave-uniform -> broadcast.
        for (int k = 0; k < HID; k += 4) {
            const float4 wr4 = *(const float4*)&whhR[k];
            const float4 wz4 = *(const float4*)&whhZ[k];
            const float4 wn4 = *(const float4*)&whhN[k];
            #pragma unroll
            for (int i = 0; i < 16; ++i) {
                const float4 h4 = *(const float4*)&h_lds[(2 * i + rr) * HPAD + k];
                aR[i]  = fmaf(h4.x, wr4.x, aR[i]);  aR[i]  = fmaf(h4.y, wr4.y, aR[i]);
                aR[i]  = fmaf(h4.z, wr4.z, aR[i]);  aR[i]  = fmaf(h4.w, wr4.w, aR[i]);
                aZ[i]  = fmaf(h4.x, wz4.x, aZ[i]);  aZ[i]  = fmaf(h4.y, wz4.y, aZ[i]);
                aZ[i]  = fmaf(h4.z, wz4.z, aZ[i]);  aZ[i]  = fmaf(h4.w, wz4.w, aZ[i]);
                aNh[i] = fmaf(h4.x, wn4.x, aNh[i]); aNh[i] = fmaf(h4.y, wn4.y, aNh[i]);
                aNh[i] = fmaf(h4.z, wn4.z, aNh[i]); aNh[i] = fmaf(h4.w, wn4.w, aNh[i]);
            }
        }
        // gi: x @ w_ih.T  (K=64)
        for (int k = 0; k < INP; k += 4) {
            const float4 wr4 = *(const float4*)&wihR[k];
            const float4 wz4 = *(const float4*)&wihZ[k];
            const float4 wn4 = *(const float4*)&wihN[k];
            #pragma unroll
            for (int i = 0; i < 16; ++i) {
                const float4 x4 = *(const float4*)&x_lds[(2 * i + rr) * INP + k];
                aR[i]  = fmaf(x4.x, wr4.x, aR[i]);  aR[i]  = fmaf(x4.y, wr4.y, aR[i]);
                aR[i]  = fmaf(x4.z, wr4.z, aR[i]);  aR[i]  = fmaf(x4.w, wr4.w, aR[i]);
                aZ[i]  = fmaf(x4.x, wz4.x, aZ[i]);  aZ[i]  = fmaf(x4.y, wz4.y, aZ[i]);
                aZ[i]  = fmaf(x4.z, wz4.z, aZ[i]);  aZ[i]  = fmaf(x4.w, wz4.w, aZ[i]);
                aNi[i] = fmaf(x4.x, wn4.x, aNi[i]); aNi[i] = fmaf(x4.y, wn4.y, aNi[i]);
                aNi[i] = fmaf(x4.z, wn4.z, aNi[i]); aNi[i] = fmaf(x4.w, wn4.w, aNi[i]);
            }
        }
        __syncthreads();   // all reads of old h/x done

        // h update: each (r=2i+rr, j) element owned by exactly this thread
        #pragma unroll
        for (int i = 0; i < 16; ++i) {
            const int r = 2 * i + rr;
            const float rg = sigf(aR[i]);
            const float zg = sigf(aZ[i]);
            const float n  = tanh_(fmaf(rg, aNh[i], aNi[i]));
            const float ho = h_lds[r * HPAD + j];
            h_lds[r * HPAD + j] = (1.0f - zg) * n + zg * ho;
        }
        __syncthreads();   // new h visible

        // fc_in: x = relu(h @ fc_in_w.T + b)  (32x64 outputs, 8 rows/thread)
        {
            float ax[8];
            #pragma unroll
            for (int i = 0; i < 8; ++i) ax[i] = fib;
            for (int k = 0; k < HID; k += 4) {
                const float4 w4 = *(const float4*)&fiw[k];
                #pragma unroll
                for (int i = 0; i < 8; ++i) {
                    const float4 h4 = *(const float4*)&h_lds[(rg4 + 4 * i) * HPAD + k];
                    ax[i] = fmaf(h4.x, w4.x, ax[i]); ax[i] = fmaf(h4.y, w4.y, ax[i]);
                    ax[i] = fmaf(h4.z, w4.z, ax[i]); ax[i] = fmaf(h4.w, w4.w, ax[i]);
                }
            }
            #pragma unroll
            for (int i = 0; i < 8; ++i)
                x_lds[(rg4 + 4 * i) * INP + jx] = fmaxf(ax[i], 0.0f);
        }

        // fc_out + softmax over 2 (wave 0 only)
        if (tid < 2 * BR) {
            const int r = tid >> 1, o = tid & 1;
            const float* fw = fc_out_w + (size_t)o * HID;
            float acc = fc_out_b[o];
            #pragma unroll
            for (int k = 0; k < HID; k += 4) {
                const float4 w4 = *(const float4*)&fw[k];
                const float4 h4 = *(const float4*)&h_lds[r * HPAD + k];
                acc = fmaf(h4.x, w4.x, acc); acc = fmaf(h4.y, w4.y, acc);
                acc = fmaf(h4.z, w4.z, acc); acc = fmaf(h4.w, w4.w, acc);
            }
            const float other = __shfl_xor(acc, 1);
            const float m  = fmaxf(acc, other);
            const float e  = __expf(acc - m);
            const float eo = __expf(other - m);
            outp[((size_t)(row0 + r) * DAYS + day) * NOUT + o] = e / (e + eo);
        }
        __syncthreads();   // x_lds writes visible before next day's gi
    }
}

extern "C" void kernel_launch(void* const* d_in, const int* in_sizes, int n_in,
                              void* d_out, int out_size, void* d_ws, size_t ws_size,
                              hipStream_t stream) {
    const float* hx       = (const float*)d_in[0];
    const float* w_ih     = (const float*)d_in[1];
    const float* w_hh     = (const float*)d_in[2];
    const float* b_ih     = (const float*)d_in[3];
    const float* b_hh     = (const float*)d_in[4];
    const float* fc_in_w  = (const float*)d_in[5];
    const float* fc_in_b  = (const float*)d_in[6];
    const float* fc_out_w = (const float*)d_in[7];
    const float* fc_out_b = (const float*)d_in[8];
    const float* span_w   = (const float*)d_in[9];
    const float* span_b   = (const float*)d_in[10];
    float* out = (float*)d_out;

    const int bs = in_sizes[0] / HID;           // 32768
    dim3 grid(bs / BR), block(NTH);
    gru_all<<<grid, block, 0, stream>>>(hx, w_ih, w_hh, b_ih, b_hh,
                                        fc_in_w, fc_in_b, fc_out_w, fc_out_b,
                                        span_w, span_b, out, bs);
}

// Round 2
// 216.752 us; speedup vs baseline: 12.1343x; 12.1343x over previous
//
#include <hip/hip_runtime.h>

#define HID 128
#define INP 64
#define SPANN 8
#define NOUT 2
#define DAYS 20
#define RT 4                 // 16-row tiles per block
#define ROWS (16*RT)         // 64 batch rows per block
#define NTH 512              // 8 waves

typedef __attribute__((ext_vector_type(8))) short short8;
typedef __attribute__((ext_vector_type(4))) float f32x4;
typedef __attribute__((ext_vector_type(2))) float f32x2;
typedef unsigned int u32;
typedef unsigned short u16;

#define MFMA(a,b,c) __builtin_amdgcn_mfma_f32_16x16x32_bf16(a,b,c,0,0,0)

__device__ __forceinline__ u16 f2bf(float f){
    union { float f; u32 u; } v; v.f = f;
    return (u16)((v.u + 0x7FFFu + ((v.u >> 16) & 1u)) >> 16);   // RNE
}
__device__ __forceinline__ u32 pack2(float a, float b){
    return (u32)f2bf(a) | ((u32)f2bf(b) << 16);
}
__device__ __forceinline__ float sigf(float x){ return 1.0f/(1.0f+__expf(-x)); }
__device__ __forceinline__ float tanhf_(float x){ return 1.0f - 2.0f/(1.0f+__expf(2.0f*x)); }

// load 8 consecutive f32 and convert to a bf16 MFMA fragment (4 VGPRs)
__device__ __forceinline__ short8 ldfrag(const float* p){
    const f32x4 a = *(const f32x4*)p;
    const f32x4 b = *(const f32x4*)(p+4);
    short8 s;
    s[0]=(short)f2bf(a[0]); s[1]=(short)f2bf(a[1]); s[2]=(short)f2bf(a[2]); s[3]=(short)f2bf(a[3]);
    s[4]=(short)f2bf(b[0]); s[5]=(short)f2bf(b[1]); s[6]=(short)f2bf(b[2]); s[7]=(short)f2bf(b[3]);
    return s;
}

// Fragment conventions (16x16x32 bf16):
//  A: lane holds A[m = l&15][k = (l>>4)*8 + j]   (weights, rows = gate cols)
//  B: lane holds B[k = (l>>4)*8 + j][n = l&15]   (h^T / x^T, n = batch row)
//  D: lane holds D[m = (l>>4)*4 + q][n = l&15]   (m89-verified)
// h/x LDS are fragment-major: for k-step ks, lane l reads 16B at ks*1024 + l*16.

__global__ __launch_bounds__(NTH, 2) void gru_mfma(
    const float* __restrict__ hx, const float* __restrict__ w_ih,
    const float* __restrict__ w_hh, const float* __restrict__ b_ih,
    const float* __restrict__ b_hh, const float* __restrict__ fc_in_w,
    const float* __restrict__ fc_in_b, const float* __restrict__ fc_out_w,
    const float* __restrict__ fc_out_b, const float* __restrict__ span_w,
    const float* __restrict__ span_b, float* __restrict__ out, int bs)
{
    __shared__ u16 hL[2][RT*2048];   // 2 x 4 tiles x (16 rows x 128 cols) bf16 = 32 KiB
    __shared__ u16 xL[2][RT*1024];   // 2 x 4 tiles x (16 rows x  64 cols) bf16 = 16 KiB

    const int tid = threadIdx.x;
    const int wid = tid >> 6;        // 0..7, owns gate tiles {wid, wid+8, wid+16}
    const int l   = tid & 63;
    const int r15 = l & 15;          // batch row within tile (B-frag col / D col)
    const int hi  = l >> 4;          // lane k-group / D row-group
    const int row0 = blockIdx.x * ROWS;

    // ---- weight fragments, cached in VGPRs for the whole kernel ----
    short8 whhR[4], whhZ[4], whhN[4];
    short8 wihR[2], wihZ[2], wihN[2];
    short8 fwA[4];                   // fc_in (wid<4) or fc_out (wid==4)
    const int g0 = wid*16 + r15;     // this lane's gate row (R section)
    #pragma unroll
    for (int ks = 0; ks < 4; ++ks){
        whhR[ks] = ldfrag(w_hh + (size_t)(      g0)*HID + ks*32 + hi*8);
        whhZ[ks] = ldfrag(w_hh + (size_t)(128 + g0)*HID + ks*32 + hi*8);
        whhN[ks] = ldfrag(w_hh + (size_t)(256 + g0)*HID + ks*32 + hi*8);
    }
    #pragma unroll
    for (int ks = 0; ks < 2; ++ks){
        wihR[ks] = ldfrag(w_ih + (size_t)(      g0)*INP + ks*32 + hi*8);
        wihZ[ks] = ldfrag(w_ih + (size_t)(128 + g0)*INP + ks*32 + hi*8);
        wihN[ks] = ldfrag(w_ih + (size_t)(256 + g0)*INP + ks*32 + hi*8);
    }
    {
        const short8 zz = {0,0,0,0,0,0,0,0};
        #pragma unroll
        for (int ks = 0; ks < 4; ++ks){
            if (wid < 4)            fwA[ks] = ldfrag(fc_in_w + (size_t)(wid*16 + r15)*HID + ks*32 + hi*8);
            else if (wid == 4)      fwA[ks] = (r15 < NOUT) ? ldfrag(fc_out_w + (size_t)r15*HID + ks*32 + hi*8) : zz;
            else                    fwA[ks] = zz;
        }
    }

    // ---- per-thread biases (D reg q <-> gate g = wid*16 + hi*4 + q) ----
    float bR[4], bZ[4], bNi[4], bNh[4], fbias[4];
    #pragma unroll
    for (int q = 0; q < 4; ++q){
        const int g = wid*16 + hi*4 + q;
        bR[q]  = b_ih[g]       + b_hh[g];
        bZ[q]  = b_ih[128 + g] + b_hh[128 + g];
        bNi[q] = b_ih[256 + g];
        bNh[q] = b_hh[256 + g];
        if (wid < 4)       fbias[q] = fc_in_b[wid*16 + hi*4 + q];
        else if (wid == 4) fbias[q] = (hi == 0 && q < NOUT) ? fc_out_b[q] : 0.0f;
        else               fbias[q] = 0.0f;
    }

    // writer u32 index inside a 2048-u16 h tile (fragment-major scatter):
    //  c = wid*16 + hi*4 + q ; ks'=c>>5, kg=(c>>3)&3, j=c&7 -> pairs (q01) are u32-adjacent
    const int wu32 = (wid>>1)*256 + (((wid&1)*2 + (hi>>1))*16 + r15)*4 + (hi&1)*2;

    // ---- h_old f32 registers + fill h buffer 0 + zero x buffer 0 ----
    float hOld[RT][4];
    const int c0 = wid*16 + hi*4;
    #pragma unroll
    for (int rt = 0; rt < RT; ++rt){
        const f32x4 h4 = *(const f32x4*)(hx + (size_t)(row0 + rt*16 + r15)*HID + c0);
        #pragma unroll
        for (int q = 0; q < 4; ++q) hOld[rt][q] = h4[q];
        u32* hb = (u32*)&hL[0][rt*2048];
        hb[wu32]     = pack2(h4[0], h4[1]);
        hb[wu32 + 1] = pack2(h4[2], h4[3]);
    }
    {
        u32* xb = (u32*)&xL[0][0];
        for (int i = tid; i < RT*512; i += NTH) xb[i] = 0u;   // x0 = zeros
    }
    __syncthreads();

    // ---- span head (wave 5): softmax(hx @ span_w.T + b), from day-0 h buffer ----
    if (wid == 5){
        const short8 zz = {0,0,0,0,0,0,0,0};
        short8 spw[4];
        #pragma unroll
        for (int ks = 0; ks < 4; ++ks)
            spw[ks] = (r15 < SPANN) ? ldfrag(span_w + (size_t)r15*HID + ks*32 + hi*8) : zz;
        float sb[4];
        #pragma unroll
        for (int q = 0; q < 4; ++q) sb[q] = (hi < 2) ? span_b[hi*4 + q] : 0.0f;
        #pragma unroll
        for (int rt = 0; rt < RT; ++rt){
            const short8* hf = (const short8*)&hL[0][rt*2048];
            f32x4 acc = {sb[0], sb[1], sb[2], sb[3]};
            #pragma unroll
            for (int ks = 0; ks < 4; ++ks) acc = MFMA(spw[ks], hf[ks*64 + l], acc);
            if (hi < 2){   // lanes 0..31 hold spans hi*4+q for row r15
                float m = fmaxf(fmaxf(acc[0], acc[1]), fmaxf(acc[2], acc[3]));
                m = fmaxf(m, __shfl_xor(m, 16));
                float e0 = __expf(acc[0]-m), e1 = __expf(acc[1]-m);
                float e2 = __expf(acc[2]-m), e3 = __expf(acc[3]-m);
                float s = e0 + e1 + e2 + e3;
                s += __shfl_xor(s, 16);
                const float inv = 1.0f / s;
                f32x4 o = {e0*inv, e1*inv, e2*inv, e3*inv};
                *(f32x4*)(out + (size_t)(row0 + rt*16 + r15)*SPANN + hi*4) = o;
            }
        }
    }

    float* __restrict__ outp = out + (size_t)bs * SPANN;

    #pragma unroll 2
    for (int day = 0; day < DAYS; ++day){
        const int p = day & 1;
        const u16* hRd = hL[p];
        const u16* xRd = xL[p];
        u32* hWr = (u32*)hL[p^1];
        u32* xWr = (u32*)xL[p^1];

        // ============ Phase A: gates + h update (all 8 waves) ============
        #pragma unroll
        for (int rt = 0; rt < RT; ++rt){
            const short8* hf = (const short8*)(hRd + rt*2048);
            const short8* xf = (const short8*)(xRd + rt*1024);
            const short8 h0 = hf[l], h1 = hf[64+l], h2 = hf[128+l], h3 = hf[192+l];
            const short8 x0 = xf[l], x1 = xf[64+l];

            f32x4 aR  = {bR[0],  bR[1],  bR[2],  bR[3]};
            f32x4 aZ  = {bZ[0],  bZ[1],  bZ[2],  bZ[3]};
            f32x4 aNh = {bNh[0], bNh[1], bNh[2], bNh[3]};
            f32x4 aNi = {bNi[0], bNi[1], bNi[2], bNi[3]};

            aR  = MFMA(whhR[0], h0, aR);  aZ  = MFMA(whhZ[0], h0, aZ);  aNh = MFMA(whhN[0], h0, aNh);
            aR  = MFMA(whhR[1], h1, aR);  aZ  = MFMA(whhZ[1], h1, aZ);  aNh = MFMA(whhN[1], h1, aNh);
            aR  = MFMA(whhR[2], h2, aR);  aZ  = MFMA(whhZ[2], h2, aZ);  aNh = MFMA(whhN[2], h2, aNh);
            aR  = MFMA(whhR[3], h3, aR);  aZ  = MFMA(whhZ[3], h3, aZ);  aNh = MFMA(whhN[3], h3, aNh);
            aR  = MFMA(wihR[0], x0, aR);  aZ  = MFMA(wihZ[0], x0, aZ);  aNi = MFMA(wihN[0], x0, aNi);
            aR  = MFMA(wihR[1], x1, aR);  aZ  = MFMA(wihZ[1], x1, aZ);  aNi = MFMA(wihN[1], x1, aNi);

            float hn[4];
            #pragma unroll
            for (int q = 0; q < 4; ++q){
                const float rg = sigf(aR[q]);
                const float zg = sigf(aZ[q]);
                const float nn = tanhf_(fmaf(rg, aNh[q], aNi[q]));
                hn[q] = nn + zg * (hOld[rt][q] - nn);
                hOld[rt][q] = hn[q];
            }
            u32* hb = hWr + rt*1024;
            hb[wu32]     = pack2(hn[0], hn[1]);
            hb[wu32 + 1] = pack2(hn[2], hn[3]);
        }
        __syncthreads();

        // ============ Phase B: fc_in (waves 0-3), fc_out+softmax (wave 4) ============
        if (wid < 4){
            #pragma unroll
            for (int rt = 0; rt < RT; ++rt){
                const short8* hf = (const short8*)(hL[p^1] + rt*2048);
                const short8 h0 = hf[l], h1 = hf[64+l], h2 = hf[128+l], h3 = hf[192+l];
                f32x4 ax = {fbias[0], fbias[1], fbias[2], fbias[3]};
                ax = MFMA(fwA[0], h0, ax);
                ax = MFMA(fwA[1], h1, ax);
                ax = MFMA(fwA[2], h2, ax);
                ax = MFMA(fwA[3], h3, ax);
                u32* xb = xWr + rt*512;
                xb[wu32]     = pack2(fmaxf(ax[0],0.0f), fmaxf(ax[1],0.0f));
                xb[wu32 + 1] = pack2(fmaxf(ax[2],0.0f), fmaxf(ax[3],0.0f));
            }
        } else if (wid == 4){
            #pragma unroll
            for (int rt = 0; rt < RT; ++rt){
                const short8* hf = (const short8*)(hL[p^1] + rt*2048);
                const short8 h0 = hf[l], h1 = hf[64+l], h2 = hf[128+l], h3 = hf[192+l];
                f32x4 ao = {fbias[0], fbias[1], fbias[2], fbias[3]};
                ao = MFMA(fwA[0], h0, ao);
                ao = MFMA(fwA[1], h1, ao);
                ao = MFMA(fwA[2], h2, ao);
                ao = MFMA(fwA[3], h3, ao);
                if (hi == 0){   // lanes 0..15 hold both logits (q=0,1) for row r15
                    const float m  = fmaxf(ao[0], ao[1]);
                    const float e0 = __expf(ao[0] - m);
                    const float e1 = __expf(ao[1] - m);
                    const float inv = 1.0f / (e0 + e1);
                    f32x2 o = {e0*inv, e1*inv};
                    *(f32x2*)(outp + ((size_t)(row0 + rt*16 + r15)*DAYS + day)*NOUT) = o;
                }
            }
        }
        __syncthreads();
    }
}

extern "C" void kernel_launch(void* const* d_in, const int* in_sizes, int n_in,
                              void* d_out, int out_size, void* d_ws, size_t ws_size,
                              hipStream_t stream) {
    const float* hx       = (const float*)d_in[0];
    const float* w_ih     = (const float*)d_in[1];
    const float* w_hh     = (const float*)d_in[2];
    const float* b_ih     = (const float*)d_in[3];
    const float* b_hh     = (const float*)d_in[4];
    const float* fc_in_w  = (const float*)d_in[5];
    const float* fc_in_b  = (const float*)d_in[6];
    const float* fc_out_w = (const float*)d_in[7];
    const float* fc_out_b = (const float*)d_in[8];
    const float* span_w   = (const float*)d_in[9];
    const float* span_b   = (const float*)d_in[10];
    float* out = (float*)d_out;

    const int bs = in_sizes[0] / HID;            // 32768
    dim3 grid(bs / ROWS), block(NTH);
    gru_mfma<<<grid, block, 0, stream>>>(hx, w_ih, w_hh, b_ih, b_hh,
                                         fc_in_w, fc_in_b, fc_out_w, fc_out_b,
                                         span_w, span_b, out, bs);
}